// Round 1
// baseline (801.913 us; speedup 1.0000x reference)
//
#include <hip/hip_runtime.h>
#include <math.h>

// Problem constants
#define NROWS  131072            // B*T
#define OUT_N  33554432          // NROWS*256
typedef unsigned int uint;

// ---- workspace layout (bytes) ----
#define WS_DIFF   0                       // double
#define C32_OFF   64                      // float [512]   |ehat_j|^2, np fp32 semantics
#define EHAT_OFF  4096                    // float [512*256]
#define EHATT_OFF (EHAT_OFF + 524288)     // float [256*512]

__device__ __forceinline__ float f4c(const float4 v, int c) {
    return c == 0 ? v.x : (c == 1 ? v.y : (c == 2 ? v.z : v.w));
}

// direct global->LDS staging, 16B/lane (gfx950 global_load_lds_dwordx4)
__device__ __forceinline__ void gl_lds16(const float4* g, float4* l) {
#if __has_builtin(__builtin_amdgcn_global_load_lds)
    __builtin_amdgcn_global_load_lds(
        (const __attribute__((address_space(1))) void*)g,
        (__attribute__((address_space(3))) void*)l, 16, 0, 0);
#else
    *l = *g;
#endif
}

// ---------------------------------------------------------------------------
// numpy pairwise_sum emulation for n=128 contiguous f32 (AVX512 build):
// 8 vector accumulators of 16 lanes, combine ((r0+r1)+(r2+r3))+((r4+r5)+(r6+r7)),
// then _mm512_reduce_add_ps tree (stride 8,4, then (u0+u2)+(u1+u3)).
// ---------------------------------------------------------------------------
__device__ __forceinline__ float np_b128_sq(const float* p) {
    float L[16];
    #pragma unroll
    for (int l = 0; l < 16; ++l) {
        float y[8];
        #pragma unroll
        for (int j = 0; j < 8; ++j) { float v = p[j * 16 + l]; y[j] = __fmul_rn(v, v); }
        L[l] = __fadd_rn(__fadd_rn(__fadd_rn(y[0], y[1]), __fadd_rn(y[2], y[3])),
                         __fadd_rn(__fadd_rn(y[4], y[5]), __fadd_rn(y[6], y[7])));
    }
    float w[8];
    #pragma unroll
    for (int l = 0; l < 8; ++l) w[l] = __fadd_rn(L[l], L[l + 8]);
    float u[4];
    #pragma unroll
    for (int l = 0; l < 4; ++l) u[l] = __fadd_rn(w[l], w[l + 4]);
    return __fadd_rn(__fadd_rn(u[0], u[2]), __fadd_rn(u[1], u[3]));
}

__device__ __forceinline__ float np_b128_nsq(const float* p, float nrm) {
    float L[16];
    #pragma unroll
    for (int l = 0; l < 16; ++l) {
        float y[8];
        #pragma unroll
        for (int j = 0; j < 8; ++j) {
            float v = __fdiv_rn(p[j * 16 + l], nrm);
            y[j] = __fmul_rn(v, v);
        }
        L[l] = __fadd_rn(__fadd_rn(__fadd_rn(y[0], y[1]), __fadd_rn(y[2], y[3])),
                         __fadd_rn(__fadd_rn(y[4], y[5]), __fadd_rn(y[6], y[7])));
    }
    float w[8];
    #pragma unroll
    for (int l = 0; l < 8; ++l) w[l] = __fadd_rn(L[l], L[l + 8]);
    float u[4];
    #pragma unroll
    for (int l = 0; l < 4; ++l) u[l] = __fadd_rn(w[l], w[l + 4]);
    return __fadd_rn(__fadd_rn(u[0], u[2]), __fadd_rn(u[1], u[3]));
}

// ---------------------------------------------------------------------------
// Kernel 1: per-codebook-row: norm32 (np semantics), Ehat + EhatT, c32.
// grid 2 x 256. Also zeroes diff accumulator.
// ---------------------------------------------------------------------------
__global__ __launch_bounds__(256) void vq_prep(
    const float* __restrict__ EMB, float* __restrict__ Ehat,
    float* __restrict__ EhatT, float* __restrict__ c32,
    double* __restrict__ diff_sum)
{
    const int e = blockIdx.x * 256 + threadIdx.x;   // 0..511
    const float* row = EMB + e * 256;
    float ss  = __fadd_rn(np_b128_sq(row), np_b128_sq(row + 128));
    float nrm = __fsqrt_rn(ss);
    for (int d = 0; d < 256; ++d) {
        float eh = __fdiv_rn(row[d], nrm);
        Ehat[e * 256 + d]  = eh;
        EhatT[d * 512 + e] = eh;
    }
    c32[e] = __fadd_rn(np_b128_nsq(row, nrm), np_b128_nsq(row + 128, nrm));
    if (e == 0) *diff_sum = 0.0;
}

// ---------------------------------------------------------------------------
// Kernel 2: fused xx (np tree) + GEMM (sequential-k fp32 FMA chains, BLAS
// semantics) + np-exact dist + first-min argmin + gather/out + diff.
// grid 2048 x 256; block = 64 rows x 512 codes, j-tile 256 (2 jc chunks).
// NEW blocking vs prior round: thread = 8 rows x 8 cols (was 4x16).
//   tj = tid&31 (32 j-lanes x 8 cols = 256 j), tmG = tid>>5 (8 groups x 8 rows).
//   B-LDS traffic per FMA halves (0.5 B/FMA); wave B-reads are 32 contiguous
//   lanes + 2-way broadcast (free) instead of 16 lanes + 4-way broadcast.
//   Staging via global_load_lds_dwordx4 (dest linear in tid).
// ---------------------------------------------------------------------------
__global__ __launch_bounds__(256, 3) void vq_main(
    const float* __restrict__ X, const float* __restrict__ EhatT,
    const float* __restrict__ Ehat, const float* __restrict__ C32,
    float* __restrict__ out, float* __restrict__ ind_out,
    double* __restrict__ diff_sum)
{
    __shared__ float4 ET4[32 * 64];     // 32 k-rows x 256 j (32 KB), k-major
    __shared__ int    indsh[64];
    __shared__ double dred[4];

    const int tid = threadIdx.x;
    const int tj  = tid & 31;           // j-lane: 32 lanes x 8 cols
    const int tmG = tid >> 5;           // row-group: 8 groups x 8 rows
    const int m0  = blockIdx.x * 64;

    const float4* Xb = (const float4*)(X + (size_t)(m0 + tmG * 8) * 256);
    const float4* Ev = (const float4*)EhatT;

    // ---- fused xx: np pairwise tree per row, 16-lane tree replicated over
    // the 32-lane j-group (lanes 16..31 duplicate 0..15; butterfly stays
    // inside each 16-lane subgroup so every lane converges to the exact
    // pairwise-tree value).
    float xxv[8];
    {
        const int tl = tj & 15;
        #pragma unroll
        for (int i = 0; i < 8; ++i) {
            const float* row = X + (size_t)(m0 + tmG * 8 + i) * 256;
            float y0[8], y1[8];
            #pragma unroll
            for (int j = 0; j < 8; ++j) {
                float v0 = row[j * 16 + tl];
                float v1 = row[128 + j * 16 + tl];
                y0[j] = __fmul_rn(v0, v0);
                y1[j] = __fmul_rn(v1, v1);
            }
            float L0 = __fadd_rn(__fadd_rn(__fadd_rn(y0[0], y0[1]), __fadd_rn(y0[2], y0[3])),
                                 __fadd_rn(__fadd_rn(y0[4], y0[5]), __fadd_rn(y0[6], y0[7])));
            float L1 = __fadd_rn(__fadd_rn(__fadd_rn(y1[0], y1[1]), __fadd_rn(y1[2], y1[3])),
                                 __fadd_rn(__fadd_rn(y1[4], y1[5]), __fadd_rn(y1[6], y1[7])));
            #pragma unroll
            for (int off = 8; off >= 1; off >>= 1) {
                L0 = __fadd_rn(L0, __shfl_xor(L0, off, 64));
                L1 = __fadd_rn(L1, __shfl_xor(L1, off, 64));
            }
            xxv[i] = __fadd_rn(L0, L1);
        }
    }

    float bd[8]; int bj[8];
    #pragma unroll
    for (int i = 0; i < 8; ++i) { bd[i] = 3.0e38f; bj[i] = 0; }

    for (int jc = 0; jc < 2; ++jc) {
        float acc[8][8];
        #pragma unroll
        for (int i = 0; i < 8; ++i)
            #pragma unroll
            for (int c = 0; c < 8; ++c) acc[i][c] = 0.0f;

        for (int kc = 0; kc < 8; ++kc) {
            __syncthreads();
            #pragma unroll
            for (int p = 0; p < 8; ++p) {
                int L  = p * 256 + tid;       // 2048 float4 in tile
                int kk = L >> 6;              // 0..31
                int j4 = L & 63;
                // dest ET4[L] is linear in tid -> wave-uniform base + lane*16
                gl_lds16(&Ev[(size_t)(kc * 32 + kk) * 128 + jc * 64 + j4], &ET4[L]);
            }
            __syncthreads();
            // d = kc*32 + k4*4 + c4 ascends: each acc[i][*] is ONE sequential
            // fp32 FMA chain over d=0..255 from 0 (BLAS sgemm rank-1 order).
            #pragma unroll
            for (int k4 = 0; k4 < 8; ++k4) {
                const int f4i = kc * 8 + k4;
                float4 a[8];
                #pragma unroll
                for (int i = 0; i < 8; ++i) a[i] = Xb[i * 64 + f4i];
                #pragma unroll
                for (int c4 = 0; c4 < 4; ++c4) {
                    const int kb = (k4 * 4 + c4) * 64;
                    float4 b0 = ET4[kb + tj];
                    float4 b1 = ET4[kb + 32 + tj];
                    #pragma unroll
                    for (int i = 0; i < 8; ++i) {
                        float av = f4c(a[i], c4);
                        acc[i][0] = fmaf(av, b0.x, acc[i][0]);
                        acc[i][1] = fmaf(av, b0.y, acc[i][1]);
                        acc[i][2] = fmaf(av, b0.z, acc[i][2]);
                        acc[i][3] = fmaf(av, b0.w, acc[i][3]);
                        acc[i][4] = fmaf(av, b1.x, acc[i][4]);
                        acc[i][5] = fmaf(av, b1.y, acc[i][5]);
                        acc[i][6] = fmaf(av, b1.z, acc[i][6]);
                        acc[i][7] = fmaf(av, b1.w, acc[i][7]);
                    }
                }
            }
        }
        // np-exact dist32 = fl32( fl32(xx - 2g) + c_j ); argmin, first-min ties.
        // Thread's j set per jc: {tj*4+c} then {128+tj*4+c}, ascending.
        const float4* C4 = (const float4*)C32;
        float4 cj0 = C4[jc * 64 + tj];
        float4 cj1 = C4[jc * 64 + 32 + tj];
        #pragma unroll
        for (int i = 0; i < 8; ++i) {
            #pragma unroll
            for (int c = 0; c < 4; ++c) {
                float g2  = __fmul_rn(2.0f, acc[i][c]);
                float d32 = __fadd_rn(__fsub_rn(xxv[i], g2), f4c(cj0, c));
                int   j   = jc * 256 + tj * 4 + c;
                if (d32 < bd[i]) { bd[i] = d32; bj[i] = j; }
            }
            #pragma unroll
            for (int c = 0; c < 4; ++c) {
                float g2  = __fmul_rn(2.0f, acc[i][c + 4]);
                float d32 = __fadd_rn(__fsub_rn(xxv[i], g2), f4c(cj1, c));
                int   j   = jc * 256 + 128 + tj * 4 + c;
                if (d32 < bd[i]) { bd[i] = d32; bj[i] = j; }
            }
        }
    }

    // merge across the 32 tj lanes: min dist, ties -> smaller index
    #pragma unroll
    for (int off = 1; off <= 16; off <<= 1) {
        #pragma unroll
        for (int i = 0; i < 8; ++i) {
            float od = __shfl_xor(bd[i], off, 64);
            int   oj = __shfl_xor(bj[i], off, 64);
            if (od < bd[i] || (od == bd[i] && oj < bj[i])) { bd[i] = od; bj[i] = oj; }
        }
    }
    if (tj == 0) {
        #pragma unroll
        for (int i = 0; i < 8; ++i) indsh[tmG * 8 + i] = bj[i];
    }

    // diff: sum of min dists (loss is lax-graded; avoids re-reading X)
    double dacc = 0.0;
    if (tj == 0) {
        #pragma unroll
        for (int i = 0; i < 8; ++i) dacc += (double)bd[i];
    }
    dacc += __shfl_xor(dacc, 32, 64);
    if ((tid & 63) == 0) dred[tid >> 6] = dacc;
    __syncthreads();
    if (tid == 0) atomicAdd(diff_sum, dred[0] + dred[1] + dred[2] + dred[3]);

    // epilogue: gather + float4 out-store (no X read)
    const float4* Eh4 = (const float4*)Ehat;
    float4* out4 = (float4*)out;
    const int cc = tid & 63;
    #pragma unroll
    for (int rr = 0; rr < 64; rr += 4) {
        int row = rr + (tid >> 6);
        int idx = indsh[row];
        out4[(size_t)(m0 + row) * 64 + cc] = Eh4[(size_t)idx * 64 + cc];
    }
    if (tid < 64) ind_out[m0 + tid] = (float)indsh[tid];
}

// ---------------------------------------------------------------------------
// Kernel 3: entropy + loss. 1 block x 256.
// ---------------------------------------------------------------------------
__global__ __launch_bounds__(256) void vq_ent_fin(
    const float* __restrict__ Ehat, const float* __restrict__ c32,
    const double* __restrict__ diff_sum, float* __restrict__ loss_out)
{
    __shared__ double red[256];
    const int tid = threadIdx.x;
    double sd = 0.0;
    for (int e = 0; e < 512; ++e) sd += (double)Ehat[e * 256 + tid];
    red[tid] = sd * sd;
    __syncthreads();
    for (int st = 128; st; st >>= 1) {
        if (tid < st) red[tid] += red[tid + st];
        __syncthreads();
    }
    double s2 = red[0];
    __syncthreads();
    red[tid] = (double)c32[tid] + (double)c32[tid + 256];
    __syncthreads();
    for (int st = 128; st; st >>= 1) {
        if (tid < st) red[tid] += red[tid + st];
        __syncthreads();
    }
    if (tid == 0) {
        double ent = 2.0 * 512.0 * red[0] - 2.0 * s2;
        *loss_out = (float)((*diff_sum) * (1.0 / (double)OUT_N)
                            - ent * (1.0 / (512.0 * 512.0)));
    }
}

// ---------------------------------------------------------------------------
extern "C" void kernel_launch(void* const* d_in, const int* in_sizes, int n_in,
                              void* d_out, int out_size, void* d_ws, size_t ws_size,
                              hipStream_t stream)
{
    const float* X   = (const float*)d_in[0];   // [32,4096,256] fp32
    const float* EMB = (const float*)d_in[1];   // [512,256] fp32

    float* out      = (float*)d_out;            // [N,D]
    float* loss_out = out + OUT_N;              // scalar
    float* ind_out  = out + OUT_N + 1;          // [N] (float-encoded indices)

    char* ws = (char*)d_ws;
    double* diff_sum = (double*)(ws + WS_DIFF);
    float*  c32      = (float*) (ws + C32_OFF);
    float*  Ehat     = (float*) (ws + EHAT_OFF);
    float*  EhatT    = (float*) (ws + EHATT_OFF);

    vq_prep<<<2, 256, 0, stream>>>(EMB, Ehat, EhatT, c32, diff_sum);
    vq_main<<<2048, 256, 0, stream>>>(X, EhatT, Ehat, c32, out, ind_out, diff_sum);
    vq_ent_fin<<<1, 256, 0, stream>>>(Ehat, c32, diff_sum, loss_out);
}

// Round 2
// 630.119 us; speedup vs baseline: 1.2726x; 1.2726x over previous
//
#include <hip/hip_runtime.h>
#include <math.h>

// Problem constants
#define NROWS  131072            // B*T
#define OUT_N  33554432          // NROWS*256
typedef unsigned int uint;

// ---- workspace layout (bytes) ----
#define WS_DIFF   0                       // double
#define C32_OFF   64                      // float [512]   |ehat_j|^2, np fp32 semantics
#define EHAT_OFF  4096                    // float [512*256]
#define EHATT_OFF (EHAT_OFF + 524288)     // float [256*512]

__device__ __forceinline__ float f4c(const float4 v, int c) {
    return c == 0 ? v.x : (c == 1 ? v.y : (c == 2 ? v.z : v.w));
}

// direct global->LDS staging, 16B/lane (gfx950 global_load_lds_dwordx4)
__device__ __forceinline__ void gl_lds16(const float4* g, float4* l) {
#if __has_builtin(__builtin_amdgcn_global_load_lds)
    __builtin_amdgcn_global_load_lds(
        (const __attribute__((address_space(1))) void*)g,
        (__attribute__((address_space(3))) void*)l, 16, 0, 0);
#else
    *l = *g;
#endif
}

// ---------------------------------------------------------------------------
// Kernel 1: per-codebook-row norm (np pairwise-tree semantics), Ehat + EhatT,
// c32.  PARALLELIZED: 32 blocks x 256 threads; 16 lanes per codebook row.
// The 16-lane shuffle butterfly (off 8/4/2/1, __fadd_rn each step) is
// bit-exact vs np_b128 pairwise_sum: off=8 == w[l]=L[l]+L[l+8],
// off=4 == u[l]=w[l]+w[l+4], off=2,1 == (u0+u2)+(u1+u3).  (Same tree already
// verified in vq_main's xx path.)
// ---------------------------------------------------------------------------
__global__ __launch_bounds__(256) void vq_prep(
    const float* __restrict__ EMB, float* __restrict__ Ehat,
    float* __restrict__ EhatT, float* __restrict__ c32,
    double* __restrict__ diff_sum)
{
    const int tid = threadIdx.x;
    const int tl  = tid & 15;
    const int rG  = tid >> 4;                 // 0..15
    const int e   = blockIdx.x * 16 + rG;     // 0..511
    const float* row = EMB + e * 256;

    // load this lane's 16 elements (lane tl holds AVX512 lane l=tl)
    float v0[8], v1[8];
    #pragma unroll
    for (int j = 0; j < 8; ++j) {
        v0[j] = row[j * 16 + tl];
        v1[j] = row[128 + j * 16 + tl];
    }
    float y0[8], y1[8];
    #pragma unroll
    for (int j = 0; j < 8; ++j) {
        y0[j] = __fmul_rn(v0[j], v0[j]);
        y1[j] = __fmul_rn(v1[j], v1[j]);
    }
    float L0 = __fadd_rn(__fadd_rn(__fadd_rn(y0[0], y0[1]), __fadd_rn(y0[2], y0[3])),
                         __fadd_rn(__fadd_rn(y0[4], y0[5]), __fadd_rn(y0[6], y0[7])));
    float L1 = __fadd_rn(__fadd_rn(__fadd_rn(y1[0], y1[1]), __fadd_rn(y1[2], y1[3])),
                         __fadd_rn(__fadd_rn(y1[4], y1[5]), __fadd_rn(y1[6], y1[7])));
    #pragma unroll
    for (int off = 8; off >= 1; off >>= 1) {
        L0 = __fadd_rn(L0, __shfl_xor(L0, off, 64));
        L1 = __fadd_rn(L1, __shfl_xor(L1, off, 64));
    }
    float ss  = __fadd_rn(L0, L1);
    float nrm = __fsqrt_rn(ss);

    // normalized writes + squared-normalized tree for c32 (np_b128_nsq order)
    float z0[8], z1[8];
    #pragma unroll
    for (int j = 0; j < 8; ++j) {
        float e0 = __fdiv_rn(v0[j], nrm);
        float e1 = __fdiv_rn(v1[j], nrm);
        Ehat[e * 256 + j * 16 + tl]       = e0;
        Ehat[e * 256 + 128 + j * 16 + tl] = e1;
        EhatT[(j * 16 + tl) * 512 + e]       = e0;
        EhatT[(128 + j * 16 + tl) * 512 + e] = e1;
        z0[j] = __fmul_rn(e0, e0);
        z1[j] = __fmul_rn(e1, e1);
    }
    float T0 = __fadd_rn(__fadd_rn(__fadd_rn(z0[0], z0[1]), __fadd_rn(z0[2], z0[3])),
                         __fadd_rn(__fadd_rn(z0[4], z0[5]), __fadd_rn(z0[6], z0[7])));
    float T1 = __fadd_rn(__fadd_rn(__fadd_rn(z1[0], z1[1]), __fadd_rn(z1[2], z1[3])),
                         __fadd_rn(__fadd_rn(z1[4], z1[5]), __fadd_rn(z1[6], z1[7])));
    #pragma unroll
    for (int off = 8; off >= 1; off >>= 1) {
        T0 = __fadd_rn(T0, __shfl_xor(T0, off, 64));
        T1 = __fadd_rn(T1, __shfl_xor(T1, off, 64));
    }
    if (tl == 0) c32[e] = __fadd_rn(T0, T1);
    if (blockIdx.x == 0 && tid == 0) *diff_sum = 0.0;
}

// ---------------------------------------------------------------------------
// Kernel 2: fused xx (np tree) + GEMM (sequential-k fp32 FMA chains, BLAS
// semantics) + np-exact dist + first-min argmin + gather/out + diff.
// grid 2048 x 256; block = 64 rows x 512 codes, j-tile 256 (2 jc chunks).
// Thread = 8 rows x 8 cols; tj = tid&31, tmG = tid>>5.
// NEW vs prior round: explicit register double-buffer of the 8 X float4s
// across k4 (and across the kc staging barrier) — the a-loads were exposed
// L2-miss latency (FETCH=3x X, VALUBusy 63%, VGPR 84 = no pipelining).
// __launch_bounds__(256,2) gives the allocator room (~190 VGPR, no spill).
// ---------------------------------------------------------------------------
__global__ __launch_bounds__(256, 2) void vq_main(
    const float* __restrict__ X, const float* __restrict__ EhatT,
    const float* __restrict__ Ehat, const float* __restrict__ C32,
    float* __restrict__ out, float* __restrict__ ind_out,
    double* __restrict__ diff_sum)
{
    __shared__ float4 ET4[32 * 64];     // 32 k-rows x 256 j (32 KB), k-major
    __shared__ int    indsh[64];
    __shared__ double dred[4];

    const int tid = threadIdx.x;
    const int tj  = tid & 31;           // j-lane: 32 lanes x 8 cols
    const int tmG = tid >> 5;           // row-group: 8 groups x 8 rows
    const int m0  = blockIdx.x * 64;

    const float4* Xb = (const float4*)(X + (size_t)(m0 + tmG * 8) * 256);
    const float4* Ev = (const float4*)EhatT;

    // ---- fused xx: np pairwise tree per row, 16-lane tree replicated over
    // the 32-lane j-group (butterfly stays inside each 16-lane subgroup).
    float xxv[8];
    {
        const int tl = tj & 15;
        #pragma unroll
        for (int i = 0; i < 8; ++i) {
            const float* row = X + (size_t)(m0 + tmG * 8 + i) * 256;
            float y0[8], y1[8];
            #pragma unroll
            for (int j = 0; j < 8; ++j) {
                float v0 = row[j * 16 + tl];
                float v1 = row[128 + j * 16 + tl];
                y0[j] = __fmul_rn(v0, v0);
                y1[j] = __fmul_rn(v1, v1);
            }
            float L0 = __fadd_rn(__fadd_rn(__fadd_rn(y0[0], y0[1]), __fadd_rn(y0[2], y0[3])),
                                 __fadd_rn(__fadd_rn(y0[4], y0[5]), __fadd_rn(y0[6], y0[7])));
            float L1 = __fadd_rn(__fadd_rn(__fadd_rn(y1[0], y1[1]), __fadd_rn(y1[2], y1[3])),
                                 __fadd_rn(__fadd_rn(y1[4], y1[5]), __fadd_rn(y1[6], y1[7])));
            #pragma unroll
            for (int off = 8; off >= 1; off >>= 1) {
                L0 = __fadd_rn(L0, __shfl_xor(L0, off, 64));
                L1 = __fadd_rn(L1, __shfl_xor(L1, off, 64));
            }
            xxv[i] = __fadd_rn(L0, L1);
        }
    }

    float bd[8]; int bj[8];
    #pragma unroll
    for (int i = 0; i < 8; ++i) { bd[i] = 3.0e38f; bj[i] = 0; }

    for (int jc = 0; jc < 2; ++jc) {
        float acc[8][8];
        #pragma unroll
        for (int i = 0; i < 8; ++i)
            #pragma unroll
            for (int c = 0; c < 8; ++c) acc[i][c] = 0.0f;

        // register prefetch for (kc=0, k4=0); L1/L2-hot from the xx pass
        float4 aN[8];
        #pragma unroll
        for (int i = 0; i < 8; ++i) aN[i] = Xb[i * 64];

        for (int kc = 0; kc < 8; ++kc) {
            __syncthreads();
            #pragma unroll
            for (int p = 0; p < 8; ++p) {
                int L  = p * 256 + tid;       // 2048 float4 in tile
                int kk = L >> 6;              // 0..31
                int j4 = L & 63;
                // dest ET4[L] is linear in tid -> wave-uniform base + lane*16
                gl_lds16(&Ev[(size_t)(kc * 32 + kk) * 128 + jc * 64 + j4], &ET4[L]);
            }
            __syncthreads();
            // d = kc*32 + k4*4 + c4 ascends: each acc[i][*] is ONE sequential
            // fp32 FMA chain over d=0..255 from 0 (BLAS sgemm rank-1 order).
            #pragma unroll
            for (int k4 = 0; k4 < 8; ++k4) {
                float4 aC[8];
                #pragma unroll
                for (int i = 0; i < 8; ++i) aC[i] = aN[i];
                // prefetch next k4 (crossing kc barrier / into jc=1: f4i=0,
                // X addresses are jc-independent so the warm-up re-load is L1-hot)
                const int nf = (k4 < 7) ? (kc * 8 + k4 + 1)
                                        : ((kc < 7) ? (kc + 1) * 8 : 0);
                #pragma unroll
                for (int i = 0; i < 8; ++i) aN[i] = Xb[i * 64 + nf];

                #pragma unroll
                for (int c4 = 0; c4 < 4; ++c4) {
                    const int kb = (k4 * 4 + c4) * 64;
                    float4 b0 = ET4[kb + tj];
                    float4 b1 = ET4[kb + 32 + tj];
                    #pragma unroll
                    for (int i = 0; i < 8; ++i) {
                        float av = f4c(aC[i], c4);
                        acc[i][0] = fmaf(av, b0.x, acc[i][0]);
                        acc[i][1] = fmaf(av, b0.y, acc[i][1]);
                        acc[i][2] = fmaf(av, b0.z, acc[i][2]);
                        acc[i][3] = fmaf(av, b0.w, acc[i][3]);
                        acc[i][4] = fmaf(av, b1.x, acc[i][4]);
                        acc[i][5] = fmaf(av, b1.y, acc[i][5]);
                        acc[i][6] = fmaf(av, b1.z, acc[i][6]);
                        acc[i][7] = fmaf(av, b1.w, acc[i][7]);
                    }
                }
            }
        }
        // np-exact dist32 = fl32( fl32(xx - 2g) + c_j ); argmin, first-min ties.
        // Thread's j set per jc: {tj*4+c} then {128+tj*4+c}, ascending.
        const float4* C4 = (const float4*)C32;
        float4 cj0 = C4[jc * 64 + tj];
        float4 cj1 = C4[jc * 64 + 32 + tj];
        #pragma unroll
        for (int i = 0; i < 8; ++i) {
            #pragma unroll
            for (int c = 0; c < 4; ++c) {
                float g2  = __fmul_rn(2.0f, acc[i][c]);
                float d32 = __fadd_rn(__fsub_rn(xxv[i], g2), f4c(cj0, c));
                int   j   = jc * 256 + tj * 4 + c;
                if (d32 < bd[i]) { bd[i] = d32; bj[i] = j; }
            }
            #pragma unroll
            for (int c = 0; c < 4; ++c) {
                float g2  = __fmul_rn(2.0f, acc[i][c + 4]);
                float d32 = __fadd_rn(__fsub_rn(xxv[i], g2), f4c(cj1, c));
                int   j   = jc * 256 + 128 + tj * 4 + c;
                if (d32 < bd[i]) { bd[i] = d32; bj[i] = j; }
            }
        }
    }

    // merge across the 32 tj lanes: min dist, ties -> smaller index
    #pragma unroll
    for (int off = 1; off <= 16; off <<= 1) {
        #pragma unroll
        for (int i = 0; i < 8; ++i) {
            float od = __shfl_xor(bd[i], off, 64);
            int   oj = __shfl_xor(bj[i], off, 64);
            if (od < bd[i] || (od == bd[i] && oj < bj[i])) { bd[i] = od; bj[i] = oj; }
        }
    }
    if (tj == 0) {
        #pragma unroll
        for (int i = 0; i < 8; ++i) indsh[tmG * 8 + i] = bj[i];
    }

    // diff: sum of min dists (loss is lax-graded; avoids re-reading X)
    double dacc = 0.0;
    if (tj == 0) {
        #pragma unroll
        for (int i = 0; i < 8; ++i) dacc += (double)bd[i];
    }
    dacc += __shfl_xor(dacc, 32, 64);
    if ((tid & 63) == 0) dred[tid >> 6] = dacc;
    __syncthreads();
    if (tid == 0) atomicAdd(diff_sum, dred[0] + dred[1] + dred[2] + dred[3]);

    // epilogue: gather + float4 out-store (no X read)
    const float4* Eh4 = (const float4*)Ehat;
    float4* out4 = (float4*)out;
    const int cc = tid & 63;
    #pragma unroll
    for (int rr = 0; rr < 64; rr += 4) {
        int row = rr + (tid >> 6);
        int idx = indsh[row];
        out4[(size_t)(m0 + row) * 64 + cc] = Eh4[(size_t)idx * 64 + cc];
    }
    if (tid < 64) ind_out[m0 + tid] = (float)indsh[tid];
}

// ---------------------------------------------------------------------------
// Kernel 3: entropy + loss. 1 block x 256.
// ---------------------------------------------------------------------------
__global__ __launch_bounds__(256) void vq_ent_fin(
    const float* __restrict__ Ehat, const float* __restrict__ c32,
    const double* __restrict__ diff_sum, float* __restrict__ loss_out)
{
    __shared__ double red[256];
    const int tid = threadIdx.x;
    double sd = 0.0;
    for (int e = 0; e < 512; ++e) sd += (double)Ehat[e * 256 + tid];
    red[tid] = sd * sd;
    __syncthreads();
    for (int st = 128; st; st >>= 1) {
        if (tid < st) red[tid] += red[tid + st];
        __syncthreads();
    }
    double s2 = red[0];
    __syncthreads();
    red[tid] = (double)c32[tid] + (double)c32[tid + 256];
    __syncthreads();
    for (int st = 128; st; st >>= 1) {
        if (tid < st) red[tid] += red[tid + st];
        __syncthreads();
    }
    if (tid == 0) {
        double ent = 2.0 * 512.0 * red[0] - 2.0 * s2;
        *loss_out = (float)((*diff_sum) * (1.0 / (double)OUT_N)
                            - ent * (1.0 / (512.0 * 512.0)));
    }
}

// ---------------------------------------------------------------------------
extern "C" void kernel_launch(void* const* d_in, const int* in_sizes, int n_in,
                              void* d_out, int out_size, void* d_ws, size_t ws_size,
                              hipStream_t stream)
{
    const float* X   = (const float*)d_in[0];   // [32,4096,256] fp32
    const float* EMB = (const float*)d_in[1];   // [512,256] fp32

    float* out      = (float*)d_out;            // [N,D]
    float* loss_out = out + OUT_N;              // scalar
    float* ind_out  = out + OUT_N + 1;          // [N] (float-encoded indices)

    char* ws = (char*)d_ws;
    double* diff_sum = (double*)(ws + WS_DIFF);
    float*  c32      = (float*) (ws + C32_OFF);
    float*  Ehat     = (float*) (ws + EHAT_OFF);
    float*  EhatT    = (float*) (ws + EHATT_OFF);

    vq_prep<<<32, 256, 0, stream>>>(EMB, Ehat, EhatT, c32, diff_sum);
    vq_main<<<2048, 256, 0, stream>>>(X, EhatT, Ehat, c32, out, ind_out, diff_sum);
    vq_ent_fin<<<1, 256, 0, stream>>>(Ehat, c32, diff_sum, loss_out);
}